// Round 13
// baseline (534.423 us; speedup 1.0000x reference)
//
#include <hip/hip_runtime.h>
#include <hip/hip_bf16.h>

#define S_N 4
#define E_N 16384
#define SEQ_N (S_N*E_N)   // 65536
#define L_N 12
#define H_N 128
#define G_N 384           // 3*H
#define DIN_N 385
#define F_N 64
#define N_NODES 50000
#define NSEL 100
#define BSEQ 16           // seqs per k_fast block (one MFMA M-tile)
#define SSEQ 16           // seqs per k_slow block
#define NSLOWB 64
#define TWO_PI_F 6.28318530717958647692f
#define LOG2E_F 1.44269504088896340736f

typedef __attribute__((ext_vector_type(8))) short s16x8;
typedef __attribute__((ext_vector_type(4))) float f32x4;
#define MFMA(a,b,c) __builtin_amdgcn_mfma_f32_16x16x32_bf16(a,b,c,0,0,0)

// ---- shared memory layout for k_slow (bytes) ----
#define SMEM_YF   0            // ushort [12][16][128] swizzled  (48 KB)
#define SMEM_YB   49152        // ushort [12][16][128] swizzled  (48 KB)
#define SMEM_HBF  98304        // ushort [2][16][128] swizzled   (8 KB)
#define SMEM_UW   106496       // float  [12][16][2]
#define SMEM_NODE 108032       // int    [16][12]  (node*1024 byte offsets)
#define SMEM_SELC 108800       // int    [16]
#define SMEM_SELI 108864       // int    [16][8]
#define SMEM_SEQV 109376       // int    [16]
#define SMEM_VALID 109440      // int    [16]
#define SMEM_ANY  109504       // int
#define SMEM_TOTAL 109568

static __device__ __forceinline__ float softplusf(float x){ return fmaxf(x,0.0f) + log1pf(__expf(-fabsf(x))); }
static __device__ __forceinline__ float sigm2(float x){
  return __builtin_amdgcn_rcpf(1.0f + __builtin_amdgcn_exp2f(-x));
}
static __device__ __forceinline__ float ntanh2(float x2){   // tanh(y), x2 = 2*log2e*y
  return fmaf(-2.0f, __builtin_amdgcn_rcpf(1.0f + __builtin_amdgcn_exp2f(x2)), 1.0f);
}
static __device__ __forceinline__ unsigned short f2bf(float f){
  unsigned int u = __float_as_uint(f);
  unsigned int r = (u + 0x7fffu + ((u>>16)&1u)) >> 16;
  return (unsigned short)r;
}
static __device__ __forceinline__ unsigned int cvtpk(float lo, float hi){
  unsigned int r;
  asm("v_cvt_pk_bf16_f32 %0, %1, %2" : "=v"(r) : "v"(lo), "v"(hi));
  return r;
}
static __device__ __forceinline__ float bfl(unsigned int u){ return __uint_as_float(u<<16); }
static __device__ __forceinline__ float bfh(unsigned int u){ return __uint_as_float(u & 0xffff0000u); }
static __device__ __forceinline__ int swzByte(int s, int j){
  return s*256 + ((j<<1) ^ ((s&7)<<4));
}
static __device__ __forceinline__ s16x8 ldsA(const char* base, int lane, int kf){
  const int row = lane & 15;
  const int byte = row*256 + (((kf<<6) + ((lane>>4)<<4)) ^ ((row&7)<<4));
  return *(const s16x8*)(base + byte);
}
static __device__ __forceinline__ s16x8 pack8(float4 u0, float4 u1){
  union { s16x8 v; unsigned int u[4]; } r;
  r.u[0]=cvtpk(u0.x,u0.y); r.u[1]=cvtpk(u0.z,u0.w);
  r.u[2]=cvtpk(u1.x,u1.y); r.u[3]=cvtpk(u1.z,u1.w);
  return r.v;
}
// pack with gate-dependent log2e prescale: nt 0..7=r, 8..15=z (x log2e), 16..23=n (x 2log2e)
static __device__ __forceinline__ void pack_one(const float* __restrict__ W,
                                                unsigned short* __restrict__ dst,
                                                int Ksrc, int KF, int idx){
  int e = idx & 7, lane = (idx>>3)&63;
  int rem = idx>>9;
  int kf = rem % KF, nt = rem / KF;
  float sc = (nt < 16) ? LOG2E_F : (2.0f*LOG2E_F);
  dst[idx] = f2bf(sc * W[(size_t)(nt*16+(lane&15))*Ksrc + kf*32+(lane>>4)*8+e]);
}

// ================= k_prep: packs + precompute (uw/trig only for non-canonical) =================
// grid 704: b<288 whh packs | <576 wih pack | <704 precompute
__global__ __launch_bounds__(512) void k_prep(
    const float* __restrict__ whh_f, const float* __restrict__ whh_b,
    const float* __restrict__ whh,   const float* __restrict__ wih,
    const int* __restrict__ walks,   const int* __restrict__ dstdeg,
    unsigned short* __restrict__ pk_whhf, unsigned short* __restrict__ pk_whhb,
    unsigned short* __restrict__ pk_whh,  unsigned short* __restrict__ pk_wih,
    int* __restrict__ wrev, float* __restrict__ uwbuf, int* __restrict__ accum,
    int* __restrict__ canonFlag, int* __restrict__ slowIdx)
{
  const int b = blockIdx.x;
  const int tid = threadIdx.x;

  if (b < 288){
    int seg = b/96;                       // 0=whh_f 1=whh_b 2=whh
    int idx = (b - seg*96)*512 + tid;     // exact: 96*512 = 24*4*64*8
    const float* W = (seg==0) ? whh_f : (seg==1) ? whh_b : whh;
    unsigned short* D = (seg==0) ? pk_whhf : (seg==1) ? pk_whhb : pk_whh;
    pack_one(W, D, H_N, 4, idx);
  } else if (b < 576){
    int idx = (b-288)*512 + tid;          // exact: 288*512 = 24*12*64*8
    pack_one(wih, pk_wih, DIN_N, 12, idx);
  } else {
    const int q = (b-576)*512 + tid;
    int wk[L_N], un[L_N];
    const int4* wp = (const int4*)(walks + (size_t)q*L_N);
    int4 w0 = wp[0], w1 = wp[1], w2 = wp[2];
    wk[0]=w0.x; wk[1]=w0.y; wk[2]=w0.z; wk[3]=w0.w;
    wk[4]=w1.x; wk[5]=w1.y; wk[6]=w1.z; wk[7]=w1.w;
    wk[8]=w2.x; wk[9]=w2.y; wk[10]=w2.z; wk[11]=w2.w;
    int ndist = 0;
    #pragma unroll
    for (int t=0;t<L_N;t++){
      int u = -1;
      for (int p=0;p<t;p++) if (wk[p]==wk[t]) { u = un[p]; break; }
      if (u < 0) u = ndist++;
      un[t] = u;
    }
    const int canon = (ndist == L_N) ? 1 : 0;
    canonFlag[q] = canon;
    int wr[L_N];
    int dmax = 0;
    #pragma unroll
    for (int tr=0;tr<L_N;tr++){
      const int node = wk[L_N-1-tr];
      wr[tr] = node;
      dmax = max(dmax, dstdeg[node]);
    }
    {
      int4* wd = (int4*)(wrev + (size_t)q*L_N);
      wd[0] = make_int4(wr[0],wr[1],wr[2],wr[3]);
      wd[1] = make_int4(wr[4],wr[5],wr[6],wr[7]);
      wd[2] = make_int4(wr[8],wr[9],wr[10],wr[11]);
    }
    if (!canon){
      int p = atomicAdd(&accum[4], 1);
      slowIdx[p] = q;
      float uwl[2*L_N];
      #pragma unroll
      for (int tr=0;tr<L_N;tr++){
        float ang = (float)un[L_N-1-tr] * (TWO_PI_F/(float)L_N);
        uwl[2*tr+0] = __sinf(ang);
        uwl[2*tr+1] = __cosf(ang);
      }
      float4* ud = (float4*)(uwbuf + 2*(size_t)q*L_N);
      #pragma unroll
      for (int v=0;v<6;v++)
        ud[v] = make_float4(uwl[4*v],uwl[4*v+1],uwl[4*v+2],uwl[4*v+3]);
    }
    for (int off=32; off; off>>=1) dmax = max(dmax, __shfl_down(dmax, off));
    if ((tid & 63)==0) atomicMax(&accum[0], dmax);
  }
}

// ---- canonical small-GRU phase via MFMA (all 16 rows identical); returns final h[unit] ----
static __device__ __forceinline__ float canon_phase(
    char* h0t, char* h1t, char* yT,
    const unsigned short* __restrict__ pk,
    const float* __restrict__ wih2, const float* __restrict__ bih2, const float* __restrict__ bhh2,
    bool bwd, int tid)
{
  const int w = tid>>6, lane = tid&63, col = lane&15, krow = lane>>4;
  const int unit = w*16 + col;
  const float cR  = (bih2[unit]     + bhh2[unit])     * LOG2E_F;
  const float cZ  = (bih2[128+unit] + bhh2[128+unit]) * LOG2E_F;
  const float cNI = bih2[256+unit] * (2.0f*LOG2E_F);
  const float cNH = bhh2[256+unit] * (2.0f*LOG2E_F);
  const float wsr = wih2[unit*2]*LOG2E_F,       wcr = wih2[unit*2+1]*LOG2E_F;
  const float wsz = wih2[(128+unit)*2]*LOG2E_F, wcz = wih2[(128+unit)*2+1]*LOG2E_F;
  const float wsn = wih2[(256+unit)*2]*(2.0f*LOG2E_F), wcn = wih2[(256+unit)*2+1]*(2.0f*LOG2E_F);

  s16x8 bw[3][4];
  #pragma unroll
  for (int i=0;i<3;i++)
    #pragma unroll
    for (int kf=0;kf<4;kf++)
      bw[i][kf] = *(const s16x8*)(pk + (size_t)(((i*8+w)*4 + kf)*64 + lane)*8);

  float hreg = 0.f;
  #pragma unroll 1
  for (int st=0; st<L_N; ++st){
    const int o = bwd ? st : (L_N-1-st);          // canonical angle index
    float ang = (float)o * (TWO_PI_F/(float)L_N);
    float sn = __sinf(ang), cs = __cosf(ang);
    const char* hr = (st&1) ? h1t : h0t;
    char*       hw = (st&1) ? h0t : h1t;
    s16x8 a0 = ldsA(hr,lane,0), a1 = ldsA(hr,lane,1), a2 = ldsA(hr,lane,2), a3 = ldsA(hr,lane,3);
    const float aRi = cR + wsr*sn + wcr*cs;
    const float aZi = cZ + wsz*sn + wcz*cs;
    const float aNIi = cNI + wsn*sn + wcn*cs;
    f32x4 aR, aZ, aNH;
    #pragma unroll
    for (int q=0;q<4;q++){ aR[q]=aRi; aZ[q]=aZi; aNH[q]=cNH; }
    aR  = MFMA(a0,bw[0][0],aR);  aR  = MFMA(a1,bw[0][1],aR);  aR  = MFMA(a2,bw[0][2],aR);  aR  = MFMA(a3,bw[0][3],aR);
    aZ  = MFMA(a0,bw[1][0],aZ);  aZ  = MFMA(a1,bw[1][1],aZ);  aZ  = MFMA(a2,bw[1][2],aZ);  aZ  = MFMA(a3,bw[1][3],aZ);
    aNH = MFMA(a0,bw[2][0],aNH); aNH = MFMA(a1,bw[2][1],aNH); aNH = MFMA(a2,bw[2][2],aNH); aNH = MFMA(a3,bw[2][3],aNH);
    float r = sigm2(aR[0]), z = sigm2(aZ[0]);
    float n = ntanh2(fmaf(r, aNH[0], aNIi));
    hreg = fmaf(z, hreg-n, n);
    unsigned short hb16 = (unsigned short)cvtpk(hreg, hreg);
    #pragma unroll
    for (int q=0;q<4;q++)
      *(unsigned short*)(hw + swzByte(krow*4+q, unit)) = hb16;
    int yrow = bwd ? (L_N-1-st) : st;
    if (krow == 0)
      *(unsigned short*)(yT + swzByte(yrow, unit)) = hb16;
    __syncthreads();
  }
  return hreg;
}

// ================= k_gx (+ fused canon block) =================
__global__ __launch_bounds__(512) void k_gx(const float* __restrict__ x,
                                            const unsigned short* __restrict__ pk_wih,
                                            const float* __restrict__ wih,
                                            const int* __restrict__ dstdeg,
                                            const int* __restrict__ accum,
                                            char* __restrict__ gxall,
                                            const unsigned short* __restrict__ pk_whhf,
                                            const unsigned short* __restrict__ pk_whhb,
                                            const float* __restrict__ wih_f, const float* __restrict__ bih_f, const float* __restrict__ bhh_f,
                                            const float* __restrict__ wih_b, const float* __restrict__ bih_b, const float* __restrict__ bhh_b,
                                            const float* __restrict__ bih,   const float* __restrict__ bhh,
                                            float* __restrict__ gposb, float* __restrict__ hc0)
{
  __shared__ char csm[4*4096];   // canon: h0t, h1t, yfT, ybT
  const int tid = threadIdx.x;
  const int w = tid>>6, lane = tid&63, col = lane&15, krow = lane>>4;
  const int unit = w*16 + col;

  if (blockIdx.x == N_NODES/16){
    char* h0t = csm;
    char* h1t = csm + 4096;
    char* yfT = csm + 8192;
    char* ybT = csm + 12288;
    for (int p = tid; p < 2048; p += 512) ((unsigned short*)h0t)[p] = 0;
    __syncthreads();
    float hb_last = canon_phase(h0t, h1t, ybT, pk_whhb, wih_b, bih_b, bhh_b, true, tid);
    for (int p = tid; p < 2048; p += 512) ((unsigned short*)h0t)[p] = 0;
    __syncthreads();
    float hf_last = canon_phase(h0t, h1t, yfT, pk_whhf, wih_f, bih_f, bhh_f, false, tid);

    s16x8 af0 = ldsA(yfT,lane,0), af1 = ldsA(yfT,lane,1), af2 = ldsA(yfT,lane,2), af3 = ldsA(yfT,lane,3);
    s16x8 ab0 = ldsA(ybT,lane,0), ab1 = ldsA(ybT,lane,1), ab2 = ldsA(ybT,lane,2), ab3 = ldsA(ybT,lane,3);
    #pragma unroll
    for (int i=0;i<3;i++){
      const int g = i*128 + unit;
      const float bia = (i<2) ? (bih[g]+bhh[g])*LOG2E_F : bih[g]*(2.0f*LOG2E_F);
      s16x8 byf[4], byb[4];
      #pragma unroll
      for (int kf=0;kf<4;kf++){
        byf[kf] = *(const s16x8*)(pk_wih + (size_t)(((i*8+w)*12 + 4+kf)*64 + lane)*8);
        byb[kf] = *(const s16x8*)(pk_wih + (size_t)(((i*8+w)*12 + 8+kf)*64 + lane)*8);
      }
      f32x4 acc;
      #pragma unroll
      for (int q=0;q<4;q++) acc[q] = bia;
      acc = MFMA(af0,byf[0],acc); acc = MFMA(af1,byf[1],acc);
      acc = MFMA(af2,byf[2],acc); acc = MFMA(af3,byf[3],acc);
      acc = MFMA(ab0,byb[0],acc); acc = MFMA(ab1,byb[1],acc);
      acc = MFMA(ab2,byb[2],acc); acc = MFMA(ab3,byb[3],acc);
      #pragma unroll
      for (int q=0;q<4;q++){
        int row = krow*4+q;
        if (row < L_N)
          gposb[row*G_N + g] = acc[q];
      }
    }
    if (krow == 0)
      hc0[unit] = 0.5f*(hf_last + hb_last);
    return;
  }

  const int m0 = blockIdx.x*16;
  const float dmaxf = (float)accum[0];
  s16x8 a[4];
  #pragma unroll
  for (int kf=0;kf<4;kf++){
    const float* xp = x + (size_t)(m0+col)*H_N + kf*32 + krow*8;
    a[kf] = pack8(*(const float4*)xp, *(const float4*)(xp+4));
  }
  float degn[4];
  #pragma unroll
  for (int q=0;q<4;q++) degn[q] = (float)dstdeg[m0 + krow*4+q] / dmaxf;
  f32x4 accg[3];
  #pragma unroll
  for (int i=0;i<3;i++){
    f32x4 acc; acc[0]=0.f; acc[1]=0.f; acc[2]=0.f; acc[3]=0.f;
    #pragma unroll
    for (int kf=0;kf<4;kf++){
      s16x8 bfr = *(const s16x8*)(pk_wih + (size_t)(((i*8+w)*12 + kf)*64 + lane)*8);
      acc = MFMA(a[kf], bfr, acc);
    }
    accg[i] = acc;
  }
  const float wdR = wih[(size_t)(unit)*DIN_N     + 384] * LOG2E_F;
  const float wdZ = wih[(size_t)(128+unit)*DIN_N + 384] * LOG2E_F;
  const float wdN = wih[(size_t)(256+unit)*DIN_N + 384] * (2.0f*LOG2E_F);
  #pragma unroll
  for (int q=0;q<4;q++){
    const size_t row = (size_t)(m0 + krow*4+q);
    float rv = accg[0][q] + wdR*degn[q];
    float zv = accg[1][q] + wdZ*degn[q];
    float nv = accg[2][q] + wdN*degn[q];
    uint2 rec;
    rec.x = cvtpk(rv, zv);
    rec.y = (unsigned int)(unsigned short)cvtpk(nv, nv);
    *(uint2*)(gxall + row*1024 + unit*8) = rec;
  }
}

// ================= k_fast: 256 threads / 4 waves; each wave owns 2 unit-groups =================
// barrier domain = 4 waves; 3 blocks/CU for cross-block overlap.
__global__ __launch_bounds__(256, 3) void k_fast(
    const char* __restrict__ gxall,
    const unsigned short* __restrict__ pk_whh,
    const float* __restrict__ bhh,
    const float* __restrict__ gposb, const float* __restrict__ hc0,
    const int* __restrict__ ssidx,
    const int* __restrict__ wrev, const int* __restrict__ canonFlag,
    float* __restrict__ out, float* __restrict__ ysel)
{
  __shared__ float gposL[L_N*G_N];     // 18432 B; aliased as f32 out-staging post-loop
  __shared__ char  hbf[2*4096];
  __shared__ float hc0L[H_N];
  __shared__ int   nodeL[BSEQ*L_N];    // node*1024 byte offsets
  __shared__ int   canonL[BSEQ];
  __shared__ int   selC[BSEQ];
  __shared__ int   selI[BSEQ*8];
  __shared__ int   selAny;

  const int tid = threadIdx.x;          // 0..255
  const int wv = tid>>6, lane = tid&63, col = lane&15, krow = lane>>4;
  const int seq0 = blockIdx.x*BSEQ;

  if (tid < BSEQ){ selC[tid] = 0; canonL[tid] = canonFlag[seq0+tid]; }
  if (tid == 0) selAny = 0;
  __syncthreads();

  for (int p = tid; p < L_N*G_N; p += 256) gposL[p] = gposb[p];
  if (tid < H_N) hc0L[tid] = hc0[tid];
  for (int p = tid; p < BSEQ*L_N; p += 256)
    nodeL[p] = wrev[(size_t)seq0*L_N + p] << 10;
  if (tid < NSEL){
    int e = ssidx[tid];
    int d = e - seq0;
    if (d >= 0 && d < BSEQ){
      int slot = atomicAdd(&selC[d], 1);
      if (slot < 8) selI[d*8+slot] = tid;
      atomicOr(&selAny, 1);
    }
  }
  __syncthreads();
  // h init: wave wv covers units wv*32 .. wv*32+31 (2 groups of 16)
  #pragma unroll
  for (int s=0;s<2;s++){
    const int u = (wv*2+s)*16 + col;
    float h0 = hc0L[u];
    unsigned int p0 = cvtpk(h0, h0);
    #pragma unroll
    for (int q=0;q<4;q++)
      *(unsigned short*)(hbf + swzByte(krow*4+q, u)) = (unsigned short)p0;
  }
  __syncthreads();

  const int hasSel = selAny;
  int uoff[2];
  float cNH[2];
  #pragma unroll
  for (int s=0;s<2;s++){
    uoff[s] = (wv*2+s)*16 + col;
    cNH[s] = bhh[256+uoff[s]] * (2.0f*LOG2E_F);
  }

  // 24 resident weight fragments: tiles {i*8 + wv*2+s} for gate i, group s
  s16x8 bhw[2][3][4];
  #pragma unroll
  for (int s=0;s<2;s++)
    #pragma unroll
    for (int i=0;i<3;i++)
      #pragma unroll
      for (int kf=0;kf<4;kf++)
        bhw[s][i][kf] = *(const s16x8*)(pk_whh + (size_t)(((i*8 + wv*2+s)*4 + kf)*64 + lane)*8);

  float hreg[2][4];
  int cf[4], scnt[4];
  #pragma unroll
  for (int q=0;q<4;q++){
    cf[q] = canonL[krow*4+q];
    int c = selC[krow*4+q]; if (c > 8) c = 8;
    scnt[q] = c;
  }
  #pragma unroll
  for (int s=0;s<2;s++)
    #pragma unroll
    for (int q=0;q<4;q++)
      hreg[s][q] = hc0L[uoff[s]];

  #pragma unroll 1
  for (int t=0; t<L_N; ++t){
    const char* hr = hbf + (t&1)*4096;
    char*       hw = hbf + ((t+1)&1)*4096;
    // issue gathers first (latency hides under ds_reads + MFMA issue of s=0)
    uint2 gv[2][4];
    #pragma unroll
    for (int q=0;q<4;q++){
      const int nb = nodeL[(krow*4+q)*L_N + t];
      gv[0][q] = *(const uint2*)(gxall + nb + uoff[0]*8);
      gv[1][q] = *(const uint2*)(gxall + nb + uoff[1]*8);
    }
    s16x8 a0 = ldsA(hr,lane,0), a1 = ldsA(hr,lane,1), a2 = ldsA(hr,lane,2), a3 = ldsA(hr,lane,3);
    #pragma unroll
    for (int s=0;s<2;s++){
      const float gpR = gposL[t*G_N + uoff[s]];
      const float gpZ = gposL[t*G_N + 128 + uoff[s]];
      const float gpN = gposL[t*G_N + 256 + uoff[s]];
      f32x4 aR, aZ, aNI, aNH;
      #pragma unroll
      for (int q=0;q<4;q++){
        aR[q]  = gpR + bfl(gv[s][q].x);
        aZ[q]  = gpZ + bfh(gv[s][q].x);
        aNI[q] = gpN + bfl(gv[s][q].y);
        aNH[q] = cNH[s];
      }
      aR  = MFMA(a0,bhw[s][0][0],aR);  aR  = MFMA(a1,bhw[s][0][1],aR);
      aR  = MFMA(a2,bhw[s][0][2],aR);  aR  = MFMA(a3,bhw[s][0][3],aR);
      aZ  = MFMA(a0,bhw[s][1][0],aZ);  aZ  = MFMA(a1,bhw[s][1][1],aZ);
      aZ  = MFMA(a2,bhw[s][1][2],aZ);  aZ  = MFMA(a3,bhw[s][1][3],aZ);
      aNH = MFMA(a0,bhw[s][2][0],aNH); aNH = MFMA(a1,bhw[s][2][1],aNH);
      aNH = MFMA(a2,bhw[s][2][2],aNH); aNH = MFMA(a3,bhw[s][2][3],aNH);
      #pragma unroll
      for (int q=0;q<4;q++){
        float r = sigm2(aR[q]), z = sigm2(aZ[q]);
        float n = ntanh2(fmaf(r, aNH[q], aNI[q]));
        hreg[s][q] = fmaf(z, hreg[s][q]-n, n);
      }
      if (t < L_N-1){
        unsigned int p01 = cvtpk(hreg[s][0], hreg[s][1]);
        unsigned int p23 = cvtpk(hreg[s][2], hreg[s][3]);
        *(unsigned short*)(hw + swzByte(krow*4+0, uoff[s])) = (unsigned short)p01;
        *(unsigned short*)(hw + swzByte(krow*4+1, uoff[s])) = (unsigned short)(p01>>16);
        *(unsigned short*)(hw + swzByte(krow*4+2, uoff[s])) = (unsigned short)p23;
        *(unsigned short*)(hw + swzByte(krow*4+3, uoff[s])) = (unsigned short)(p23>>16);
        if (hasSel){
          #pragma unroll
          for (int q=0;q<4;q++){
            const int row = krow*4+q;
            if (cf[q])
              for (int m=0;m<scnt[q];m++)
                ysel[((size_t)selI[row*8+m]*(L_N-1) + t)*H_N + uoff[s]] = hreg[s][q];
          }
        }
      }
    }
    if (t < L_N-1) __syncthreads();
  }
  // ---- coalesced out: stage f32 h in LDS (alias gposL), write float4 full lines ----
  // non-canonical rows get (finite) garbage here; k_slow overwrites them later in-stream.
  __syncthreads();
  #pragma unroll
  for (int s=0;s<2;s++)
    #pragma unroll
    for (int q=0;q<4;q++)
      gposL[(krow*4+q)*H_N + uoff[s]] = hreg[s][q];
  __syncthreads();
  for (int p = tid; p < BSEQ*H_N/4; p += 256){
    float4 v = ((const float4*)gposL)[p];
    ((float4*)(out + (size_t)seq0*H_N))[p] = v;
  }
}

// ================= slow path small-GRU phase (pre-scaled) =================
static __device__ __forceinline__ void small_gru_phase(
    char* smem, const unsigned short* __restrict__ pk,
    const float* __restrict__ wih2, const float* __restrict__ bih2, const float* __restrict__ bhh2,
    bool bwd, char* ySt, float* hreg, int tid)
{
  const int w = tid>>6, lane = tid&63, col = lane&15, krow = lane>>4;
  const int unit = w*16 + col;
  char* hbf = smem + SMEM_HBF;
  const float* uwF = (const float*)(smem + SMEM_UW);

  const float cR  = (bih2[unit]     + bhh2[unit])     * LOG2E_F;
  const float cZ  = (bih2[128+unit] + bhh2[128+unit]) * LOG2E_F;
  const float cNI = bih2[256+unit] * (2.0f*LOG2E_F);
  const float cNH = bhh2[256+unit] * (2.0f*LOG2E_F);
  const float wsr = wih2[unit*2]*LOG2E_F,       wcr = wih2[unit*2+1]*LOG2E_F;
  const float wsz = wih2[(128+unit)*2]*LOG2E_F, wcz = wih2[(128+unit)*2+1]*LOG2E_F;
  const float wsn = wih2[(256+unit)*2]*(2.0f*LOG2E_F), wcn = wih2[(256+unit)*2+1]*(2.0f*LOG2E_F);

  s16x8 bw[3][4];
  #pragma unroll
  for (int i=0;i<3;i++)
    #pragma unroll
    for (int kf=0;kf<4;kf++)
      bw[i][kf] = *(const s16x8*)(pk + (size_t)(((i*8+w)*4 + kf)*64 + lane)*8);

  #pragma unroll 1
  for (int st=0; st<L_N; ++st){
    const int o = bwd ? (L_N-1-st) : st;
    const char* hr = hbf + (st&1)*4096;
    char*       hw = hbf + ((st+1)&1)*4096;
    float sn[4], cs[4];
    #pragma unroll
    for (int q=0;q<4;q++){
      int row = krow*4+q;
      sn[q] = uwF[(o*16+row)*2+0]; cs[q] = uwF[(o*16+row)*2+1];
    }
    s16x8 a0 = ldsA(hr,lane,0), a1 = ldsA(hr,lane,1), a2 = ldsA(hr,lane,2), a3 = ldsA(hr,lane,3);
    f32x4 aR, aZ, aNH;
    #pragma unroll
    for (int q=0;q<4;q++){
      aR[q]  = cR + wsr*sn[q] + wcr*cs[q];
      aZ[q]  = cZ + wsz*sn[q] + wcz*cs[q];
      aNH[q] = cNH;
    }
    aR  = MFMA(a0,bw[0][0],aR);  aR  = MFMA(a1,bw[0][1],aR);  aR  = MFMA(a2,bw[0][2],aR);  aR  = MFMA(a3,bw[0][3],aR);
    aZ  = MFMA(a0,bw[1][0],aZ);  aZ  = MFMA(a1,bw[1][1],aZ);  aZ  = MFMA(a2,bw[1][2],aZ);  aZ  = MFMA(a3,bw[1][3],aZ);
    aNH = MFMA(a0,bw[2][0],aNH); aNH = MFMA(a1,bw[2][1],aNH); aNH = MFMA(a2,bw[2][2],aNH); aNH = MFMA(a3,bw[2][3],aNH);
    #pragma unroll
    for (int q=0;q<4;q++){
      int row = krow*4+q;
      float r = sigm2(aR[q]), z = sigm2(aZ[q]);
      float ni = cNI + wsn*sn[q] + wcn*cs[q];
      float n = ntanh2(fmaf(r, aNH[q], ni));
      float h = fmaf(z, hreg[q]-n, n);
      hreg[q] = h;
      unsigned int pp = cvtpk(h, h);
      *(unsigned short*)(hw + swzByte(row,unit)) = (unsigned short)pp;
      *(unsigned short*)(ySt + st*4096 + swzByte(row,unit)) = (unsigned short)pp;
    }
    __syncthreads();
  }
}

// ================= k_slow: grid-stride over non-canonical walks =================
__global__ __launch_bounds__(512, 2) void k_slow(
    const char* __restrict__ gxall,
    const unsigned short* __restrict__ pk_whhf, const unsigned short* __restrict__ pk_whhb,
    const unsigned short* __restrict__ pk_whh,  const unsigned short* __restrict__ pk_wih,
    const float* __restrict__ wihf, const float* __restrict__ bihf, const float* __restrict__ bhhf,
    const float* __restrict__ wihb, const float* __restrict__ bihb, const float* __restrict__ bhhb,
    const float* __restrict__ bih,  const float* __restrict__ bhh,
    const int* __restrict__ ssidx,
    const int* __restrict__ wrev, const float* __restrict__ uwbuf,
    const int* __restrict__ slowIdx, const int* __restrict__ slowCnt,
    float* __restrict__ out, float* __restrict__ ysel)
{
  extern __shared__ char smem[];
  char*  hbf   = smem + SMEM_HBF;
  float* uwF   = (float*)(smem + SMEM_UW);
  int*   nodeL = (int*)(smem + SMEM_NODE);
  int*   selC  = (int*)(smem + SMEM_SELC);
  int*   selI  = (int*)(smem + SMEM_SELI);
  int*   seqV  = (int*)(smem + SMEM_SEQV);
  int*   validL= (int*)(smem + SMEM_VALID);
  int*   anyP  = (int*)(smem + SMEM_ANY);

  const int cnt = *slowCnt;
  const int tid = threadIdx.x;
  const int w = tid>>6, lane = tid&63, col = lane&15, krow = lane>>4;
  const int unit = w*16 + col;
  const int unit8 = unit*8;

  s16x8 byf[3][4], byb[3][4], bhw[3][4];
  #pragma unroll
  for (int i=0;i<3;i++){
    #pragma unroll
    for (int kf=0;kf<4;kf++){
      byf[i][kf] = *(const s16x8*)(pk_wih + (size_t)(((i*8+w)*12 + 4+kf)*64 + lane)*8);
      byb[i][kf] = *(const s16x8*)(pk_wih + (size_t)(((i*8+w)*12 + 8+kf)*64 + lane)*8);
      bhw[i][kf] = *(const s16x8*)(pk_whh + (size_t)(((i*8+w)*4  +   kf)*64 + lane)*8);
    }
  }
  const float cR  = (bih[unit]     + bhh[unit])     * LOG2E_F;
  const float cZ  = (bih[128+unit] + bhh[128+unit]) * LOG2E_F;
  const float cNI = bih[256+unit] * (2.0f*LOG2E_F);
  const float cNH = bhh[256+unit] * (2.0f*LOG2E_F);

  for (int base = blockIdx.x*SSEQ; base < cnt; base += NSLOWB*SSEQ){

    if (tid < SSEQ){
      int idx = base + tid;
      int v = (idx < cnt) ? 1 : 0;
      seqV[tid]   = v ? slowIdx[idx] : slowIdx[base];
      validL[tid] = v;
      selC[tid] = 0;
    }
    if (tid == 0) *anyP = 0;
    __syncthreads();

    for (int p = tid; p < SSEQ*L_N; p += 512){
      int si = p / L_N, t = p - si*L_N;
      int sq = seqV[si];
      nodeL[p] = wrev[(size_t)sq*L_N + t] << 10;
      uwF[(t*16+si)*2+0] = uwbuf[2*((size_t)sq*L_N + t)+0];
      uwF[(t*16+si)*2+1] = uwbuf[2*((size_t)sq*L_N + t)+1];
    }
    if (tid < NSEL){
      int e = ssidx[tid];
      for (int si=0; si<SSEQ; si++){
        if (validL[si] && seqV[si]==e){
          int slot = atomicAdd(&selC[si], 1);
          if (slot < 8) selI[si*8+slot] = tid;
          atomicOr(anyP, 1);
        }
      }
    }
    #pragma unroll
    for (int q=0;q<4;q++)
      *(unsigned short*)(hbf + swzByte(krow*4+q, unit)) = 0;
    __syncthreads();
    const int hasSel = *anyP;

    float hreg[4] = {0.f,0.f,0.f,0.f};

    small_gru_phase(smem, pk_whhb, wihb, bihb, bhhb, true,  smem+SMEM_YB, hreg, tid);
    float hb[4];
    #pragma unroll
    for (int q=0;q<4;q++){
      hb[q]=hreg[q]; hreg[q]=0.f;
      *(unsigned short*)(hbf + swzByte(krow*4+q, unit)) = 0;
    }
    __syncthreads();
    small_gru_phase(smem, pk_whhf, wihf, bihf, bhhf, false, smem+SMEM_YF, hreg, tid);
    #pragma unroll
    for (int q=0;q<4;q++){
      hreg[q] = 0.5f*(hreg[q]+hb[q]);
      *(unsigned short*)(hbf + swzByte(krow*4+q, unit)) = (unsigned short)cvtpk(hreg[q], hreg[q]);
    }
    __syncthreads();

    uint2 gv[4];
    #pragma unroll
    for (int q=0;q<4;q++){
      int nb = nodeL[(krow*4+q)*L_N + 0];
      gv[q] = *(const uint2*)(gxall + nb + unit8);
    }

    #pragma unroll 1
    for (int t=0; t<L_N; ++t){
      const char* hr = hbf + (t&1)*4096;
      char*       hw = hbf + ((t+1)&1)*4096;
      f32x4 aR, aZ, aNI, aNH;
      #pragma unroll
      for (int q=0;q<4;q++){
        aR[q]  = cR  + bfl(gv[q].x);
        aZ[q]  = cZ  + bfh(gv[q].x);
        aNI[q] = cNI + bfl(gv[q].y);
        aNH[q] = cNH;
      }
      if (t+1 < L_N){
        #pragma unroll
        for (int q=0;q<4;q++){
          int nb = nodeL[(krow*4+q)*L_N + t+1];
          gv[q] = *(const uint2*)(gxall + nb + unit8);
        }
      }
      {
        s16x8 a0 = ldsA(hr,lane,0), a1 = ldsA(hr,lane,1), a2 = ldsA(hr,lane,2), a3 = ldsA(hr,lane,3);
        aR  = MFMA(a0,bhw[0][0],aR);  aR  = MFMA(a1,bhw[0][1],aR);  aR  = MFMA(a2,bhw[0][2],aR);  aR  = MFMA(a3,bhw[0][3],aR);
        aZ  = MFMA(a0,bhw[1][0],aZ);  aZ  = MFMA(a1,bhw[1][1],aZ);  aZ  = MFMA(a2,bhw[1][2],aZ);  aZ  = MFMA(a3,bhw[1][3],aZ);
        aNH = MFMA(a0,bhw[2][0],aNH); aNH = MFMA(a1,bhw[2][1],aNH); aNH = MFMA(a2,bhw[2][2],aNH); aNH = MFMA(a3,bhw[2][3],aNH);
      }
      {
        const char* yfb = smem + SMEM_YF + t*4096;
        s16x8 f0 = ldsA(yfb,lane,0), f1 = ldsA(yfb,lane,1), f2 = ldsA(yfb,lane,2), f3 = ldsA(yfb,lane,3);
        aR  = MFMA(f0,byf[0][0],aR);  aR  = MFMA(f1,byf[0][1],aR);  aR  = MFMA(f2,byf[0][2],aR);  aR  = MFMA(f3,byf[0][3],aR);
        aZ  = MFMA(f0,byf[1][0],aZ);  aZ  = MFMA(f1,byf[1][1],aZ);  aZ  = MFMA(f2,byf[1][2],aZ);  aZ  = MFMA(f3,byf[1][3],aZ);
        aNI = MFMA(f0,byf[2][0],aNI); aNI = MFMA(f1,byf[2][1],aNI); aNI = MFMA(f2,byf[2][2],aNI); aNI = MFMA(f3,byf[2][3],aNI);
      }
      {
        const char* ybb = smem + SMEM_YB + (L_N-1-t)*4096;
        s16x8 g0 = ldsA(ybb,lane,0), g1 = ldsA(ybb,lane,1), g2 = ldsA(ybb,lane,2), g3 = ldsA(ybb,lane,3);
        aR  = MFMA(g0,byb[0][0],aR);  aR  = MFMA(g1,byb[0][1],aR);  aR  = MFMA(g2,byb[0][2],aR);  aR  = MFMA(g3,byb[0][3],aR);
        aZ  = MFMA(g0,byb[1][0],aZ);  aZ  = MFMA(g1,byb[1][1],aZ);  aZ  = MFMA(g2,byb[1][2],aZ);  aZ  = MFMA(g3,byb[1][3],aZ);
        aNI = MFMA(g0,byb[2][0],aNI); aNI = MFMA(g1,byb[2][1],aNI); aNI = MFMA(g2,byb[2][2],aNI); aNI = MFMA(g3,byb[2][3],aNI);
      }
      #pragma unroll
      for (int q=0;q<4;q++){
        const int row = krow*4+q;
        float r = sigm2(aR[q]), z = sigm2(aZ[q]);
        float n = ntanh2(fmaf(r, aNH[q], aNI[q]));
        float h = fmaf(z, hreg[q]-n, n);
        hreg[q] = h;
        *(unsigned short*)(hw + swzByte(row,unit)) = (unsigned short)cvtpk(h, h);
        if (t == L_N-1){
          if (validL[row])
            out[(size_t)seqV[row]*H_N + unit] = h;
        }
      }
      if (hasSel && t < L_N-1){
        #pragma unroll
        for (int q=0;q<4;q++){
          const int row = krow*4+q;
          int c = selC[row]; if (c > 8) c = 8;
          for (int m=0;m<c;m++)
            ysel[((size_t)selI[row*8+m]*(L_N-1) + t)*H_N + unit] = hreg[q];
        }
      }
      __syncthreads();
    }
  }
}

// ================= loss (finalize folded in; chain-broken inner product) =================
__global__ __launch_bounds__(64) void k_loss(
    const float* __restrict__ ysel, const float* __restrict__ y0,
    const int* __restrict__ wrev, const int* __restrict__ ssidx,
    const float* __restrict__ fcw, const float* __restrict__ fcb,
    float* __restrict__ accum, float* __restrict__ out)
{
  const int i = blockIdx.x;
  const int f = threadIdx.x;
  __shared__ __align__(16) float yh[H_N];
  const int seq = ssidx[i];
  float A=0.0f, B=0.0f, Sy=0.0f;
  const float bias = fcb[f];
  const float4* fr = (const float4*)(fcw + (size_t)f*H_N);
  for (int t=0;t<L_N-1;t++){
    for (int k=f;k<H_N;k+=64) yh[k] = ysel[((size_t)i*(L_N-1)+t)*H_N + k];
    __syncthreads();
    float l0=0.f,l1=0.f,l2=0.f,l3=0.f;
    const float4* y4 = (const float4*)yh;
    #pragma unroll 8
    for (int k4=0;k4<H_N/4;k4++){
      float4 wv = fr[k4];
      float4 yv = y4[k4];
      l0 = fmaf(wv.x, yv.x, l0);
      l1 = fmaf(wv.y, yv.y, l1);
      l2 = fmaf(wv.z, yv.z, l2);
      l3 = fmaf(wv.w, yv.w, l3);
    }
    float lg = bias + ((l0+l1)+(l2+l3));
    const int node = wrev[(size_t)seq*L_N + t + 1];
    const float yt = y0[(size_t)node*F_N + f];
    A += yt * softplusf(-lg);
    B += (1.0f-yt) * softplusf(lg);
    Sy += yt;
    __syncthreads();
  }
  for (int off=32; off; off>>=1){
    A += __shfl_down(A,off); B += __shfl_down(B,off); Sy += __shfl_down(Sy,off);
  }
  if (f==0){
    atomicAdd(&accum[1],A); atomicAdd(&accum[2],B); atomicAdd(&accum[3],Sy);
    __threadfence();
    unsigned int done = atomicAdd((unsigned int*)&accum[5], 1u);
    if (done == NSEL-1){
      float As = atomicAdd(&accum[1], 0.0f);
      float Bs = atomicAdd(&accum[2], 0.0f);
      float Ss = atomicAdd(&accum[3], 0.0f);
      out[(size_t)SEQ_N*H_N] = As/Ss + Bs/(float)(NSEL*(L_N-1)*F_N);
    }
  }
}

extern "C" void kernel_launch(void* const* d_in, const int* in_sizes, int n_in,
                              void* d_out, int out_size, void* d_ws, size_t ws_size,
                              hipStream_t stream)
{
  const float* x     = (const float*)d_in[0];
  const float* y0    = (const float*)d_in[1];
  const float* wih_f = (const float*)d_in[2];
  const float* whh_f = (const float*)d_in[3];
  const float* bih_f = (const float*)d_in[4];
  const float* bhh_f = (const float*)d_in[5];
  const float* wih_b = (const float*)d_in[6];
  const float* whh_b = (const float*)d_in[7];
  const float* bih_b = (const float*)d_in[8];
  const float* bhh_b = (const float*)d_in[9];
  const float* wih   = (const float*)d_in[10];
  const float* whh   = (const float*)d_in[11];
  const float* bih   = (const float*)d_in[12];
  const float* bhh   = (const float*)d_in[13];
  const float* fc_w  = (const float*)d_in[14];
  const float* fc_b  = (const float*)d_in[15];
  const int*   walks = (const int*)d_in[16];
  const int*   dstdeg= (const int*)d_in[17];
  const int*   ssidx = (const int*)d_in[18];
  (void)in_sizes; (void)n_in; (void)out_size; (void)ws_size;

  char* ws = (char*)d_ws;
  size_t off = 0;
  auto wsalloc = [&](size_t bytes)->void* {
    void* p = ws + off; off += (bytes + 255) & ~(size_t)255; return p;
  };
  int*   accum_i = (int*)wsalloc(32);   // [0]=degmax [1..3]=loss [4]=slowCnt [5]=done
  float* accum_f = (float*)accum_i;
  int*   wrev   = (int*)  wsalloc(sizeof(int)  * SEQ_N * L_N);
  float* uwbuf  = (float*)wsalloc(sizeof(float)* SEQ_N * L_N * 2);
  unsigned short* pk_whhf = (unsigned short*)wsalloc(2u*24*4*64*8);
  unsigned short* pk_whhb = (unsigned short*)wsalloc(2u*24*4*64*8);
  unsigned short* pk_whh  = (unsigned short*)wsalloc(2u*24*4*64*8);
  unsigned short* pk_wih  = (unsigned short*)wsalloc(2u*24*12*64*8);
  float* ysel   = (float*)wsalloc(sizeof(float)* NSEL * (L_N-1) * H_N);
  char*  gxall  = (char*)wsalloc((size_t)N_NODES*1024);
  int*   canonFlag = (int*)wsalloc(sizeof(int)*SEQ_N);
  int*   slowIdxA  = (int*)wsalloc(sizeof(int)*SEQ_N);
  float* gposb = (float*)wsalloc(sizeof(float)*L_N*G_N);
  float* hc0   = (float*)wsalloc(sizeof(float)*H_N);

  hipMemsetAsync(accum_i, 0, 32, stream);
  k_prep<<<704, 512, 0, stream>>>(
      whh_f, whh_b, whh, wih,
      walks, dstdeg,
      pk_whhf, pk_whhb, pk_whh, pk_wih,
      wrev, uwbuf, accum_i, canonFlag, slowIdxA);
  k_gx<<<N_NODES/16 + 1, 512, 0, stream>>>(x, pk_wih, wih, dstdeg, accum_i, gxall,
      pk_whhf, pk_whhb,
      wih_f, bih_f, bhh_f,
      wih_b, bih_b, bhh_b,
      bih, bhh, gposb, hc0);
  k_fast<<<SEQ_N/BSEQ, 256, 0, stream>>>(gxall, pk_whh, bhh,
      gposb, hc0, ssidx, wrev, canonFlag,
      (float*)d_out, ysel);
  hipFuncSetAttribute(reinterpret_cast<const void*>(k_slow),
                      hipFuncAttributeMaxDynamicSharedMemorySize, SMEM_TOTAL);
  k_slow<<<NSLOWB, 512, SMEM_TOTAL, stream>>>(gxall,
      pk_whhf, pk_whhb, pk_whh, pk_wih,
      wih_f, bih_f, bhh_f,
      wih_b, bih_b, bhh_b,
      bih, bhh,
      ssidx, wrev, uwbuf,
      slowIdxA, accum_i+4,
      (float*)d_out, ysel);
  k_loss<<<NSEL, 64, 0, stream>>>(ysel, y0, wrev, ssidx, fc_w, fc_b, accum_f, (float*)d_out);
}

// Round 14
// 400.477 us; speedup vs baseline: 1.3345x; 1.3345x over previous
//
#include <hip/hip_runtime.h>
#include <hip/hip_bf16.h>

#define S_N 4
#define E_N 16384
#define SEQ_N (S_N*E_N)   // 65536
#define L_N 12
#define H_N 128
#define G_N 384           // 3*H
#define DIN_N 385
#define F_N 64
#define N_NODES 50000
#define NSEL 100
#define BSEQ 16           // seqs per k_fast block (one MFMA M-tile)
#define SSEQ 16           // seqs per k_slow block
#define NSLOWB 64
#define TWO_PI_F 6.28318530717958647692f
#define LOG2E_F 1.44269504088896340736f

typedef __attribute__((ext_vector_type(8))) short s16x8;
typedef __attribute__((ext_vector_type(4))) float f32x4;
#define MFMA(a,b,c) __builtin_amdgcn_mfma_f32_16x16x32_bf16(a,b,c,0,0,0)

// ---- shared memory layout for k_slow (bytes) ----
#define SMEM_YF   0            // ushort [12][16][128] swizzled  (48 KB)
#define SMEM_YB   49152        // ushort [12][16][128] swizzled  (48 KB)
#define SMEM_HBF  98304        // ushort [2][16][128] swizzled   (8 KB)
#define SMEM_UW   106496       // float  [12][16][2]
#define SMEM_NODE 108032       // int    [16][12]  (node*1024 byte offsets)
#define SMEM_SELC 108800       // int    [16]
#define SMEM_SELI 108864       // int    [16][8]
#define SMEM_SEQV 109376       // int    [16]
#define SMEM_VALID 109440      // int    [16]
#define SMEM_ANY  109504       // int
#define SMEM_TOTAL 109568

static __device__ __forceinline__ float softplusf(float x){ return fmaxf(x,0.0f) + log1pf(__expf(-fabsf(x))); }
static __device__ __forceinline__ float sigm2(float x){
  return __builtin_amdgcn_rcpf(1.0f + __builtin_amdgcn_exp2f(-x));
}
static __device__ __forceinline__ float ntanh2(float x2){   // tanh(y), x2 = 2*log2e*y
  return fmaf(-2.0f, __builtin_amdgcn_rcpf(1.0f + __builtin_amdgcn_exp2f(x2)), 1.0f);
}
static __device__ __forceinline__ unsigned short f2bf(float f){
  unsigned int u = __float_as_uint(f);
  unsigned int r = (u + 0x7fffu + ((u>>16)&1u)) >> 16;
  return (unsigned short)r;
}
static __device__ __forceinline__ unsigned int cvtpk(float lo, float hi){
  unsigned int r;
  asm("v_cvt_pk_bf16_f32 %0, %1, %2" : "=v"(r) : "v"(lo), "v"(hi));
  return r;
}
static __device__ __forceinline__ float bfl(unsigned int u){ return __uint_as_float(u<<16); }
static __device__ __forceinline__ float bfh(unsigned int u){ return __uint_as_float(u & 0xffff0000u); }
static __device__ __forceinline__ int swzByte(int s, int j){
  return s*256 + ((j<<1) ^ ((s&7)<<4));
}
static __device__ __forceinline__ s16x8 ldsA(const char* base, int lane, int kf){
  const int row = lane & 15;
  const int byte = row*256 + (((kf<<6) + ((lane>>4)<<4)) ^ ((row&7)<<4));
  return *(const s16x8*)(base + byte);
}
static __device__ __forceinline__ s16x8 pack8(float4 u0, float4 u1){
  union { s16x8 v; unsigned int u[4]; } r;
  r.u[0]=cvtpk(u0.x,u0.y); r.u[1]=cvtpk(u0.z,u0.w);
  r.u[2]=cvtpk(u1.x,u1.y); r.u[3]=cvtpk(u1.z,u1.w);
  return r.v;
}
// pack with gate-dependent log2e prescale: nt 0..7=r, 8..15=z (x log2e), 16..23=n (x 2log2e)
static __device__ __forceinline__ void pack_one(const float* __restrict__ W,
                                                unsigned short* __restrict__ dst,
                                                int Ksrc, int KF, int idx){
  int e = idx & 7, lane = (idx>>3)&63;
  int rem = idx>>9;
  int kf = rem % KF, nt = rem / KF;
  float sc = (nt < 16) ? LOG2E_F : (2.0f*LOG2E_F);
  dst[idx] = f2bf(sc * W[(size_t)(nt*16+(lane&15))*Ksrc + kf*32+(lane>>4)*8+e]);
}

// ================= k_prep: packs + precompute (uw/trig only for non-canonical) =================
// grid 704: b<288 whh packs | <576 wih pack | <704 precompute
__global__ __launch_bounds__(512) void k_prep(
    const float* __restrict__ whh_f, const float* __restrict__ whh_b,
    const float* __restrict__ whh,   const float* __restrict__ wih,
    const int* __restrict__ walks,   const int* __restrict__ dstdeg,
    unsigned short* __restrict__ pk_whhf, unsigned short* __restrict__ pk_whhb,
    unsigned short* __restrict__ pk_whh,  unsigned short* __restrict__ pk_wih,
    int* __restrict__ wrev, float* __restrict__ uwbuf, int* __restrict__ accum,
    int* __restrict__ canonFlag, int* __restrict__ slowIdx)
{
  const int b = blockIdx.x;
  const int tid = threadIdx.x;

  if (b < 288){
    int seg = b/96;                       // 0=whh_f 1=whh_b 2=whh
    int idx = (b - seg*96)*512 + tid;     // exact: 96*512 = 24*4*64*8
    const float* W = (seg==0) ? whh_f : (seg==1) ? whh_b : whh;
    unsigned short* D = (seg==0) ? pk_whhf : (seg==1) ? pk_whhb : pk_whh;
    pack_one(W, D, H_N, 4, idx);
  } else if (b < 576){
    int idx = (b-288)*512 + tid;          // exact: 288*512 = 24*12*64*8
    pack_one(wih, pk_wih, DIN_N, 12, idx);
  } else {
    const int q = (b-576)*512 + tid;
    int wk[L_N], un[L_N];
    const int4* wp = (const int4*)(walks + (size_t)q*L_N);
    int4 w0 = wp[0], w1 = wp[1], w2 = wp[2];
    wk[0]=w0.x; wk[1]=w0.y; wk[2]=w0.z; wk[3]=w0.w;
    wk[4]=w1.x; wk[5]=w1.y; wk[6]=w1.z; wk[7]=w1.w;
    wk[8]=w2.x; wk[9]=w2.y; wk[10]=w2.z; wk[11]=w2.w;
    int ndist = 0;
    #pragma unroll
    for (int t=0;t<L_N;t++){
      int u = -1;
      for (int p=0;p<t;p++) if (wk[p]==wk[t]) { u = un[p]; break; }
      if (u < 0) u = ndist++;
      un[t] = u;
    }
    const int canon = (ndist == L_N) ? 1 : 0;
    canonFlag[q] = canon;
    int wr[L_N];
    int dmax = 0;
    #pragma unroll
    for (int tr=0;tr<L_N;tr++){
      const int node = wk[L_N-1-tr];
      wr[tr] = node;
      dmax = max(dmax, dstdeg[node]);
    }
    {
      int4* wd = (int4*)(wrev + (size_t)q*L_N);
      wd[0] = make_int4(wr[0],wr[1],wr[2],wr[3]);
      wd[1] = make_int4(wr[4],wr[5],wr[6],wr[7]);
      wd[2] = make_int4(wr[8],wr[9],wr[10],wr[11]);
    }
    if (!canon){
      int p = atomicAdd(&accum[4], 1);
      slowIdx[p] = q;
      float uwl[2*L_N];
      #pragma unroll
      for (int tr=0;tr<L_N;tr++){
        float ang = (float)un[L_N-1-tr] * (TWO_PI_F/(float)L_N);
        uwl[2*tr+0] = __sinf(ang);
        uwl[2*tr+1] = __cosf(ang);
      }
      float4* ud = (float4*)(uwbuf + 2*(size_t)q*L_N);
      #pragma unroll
      for (int v=0;v<6;v++)
        ud[v] = make_float4(uwl[4*v],uwl[4*v+1],uwl[4*v+2],uwl[4*v+3]);
    }
    for (int off=32; off; off>>=1) dmax = max(dmax, __shfl_down(dmax, off));
    if ((tid & 63)==0) atomicMax(&accum[0], dmax);
  }
}

// ---- canonical small-GRU phase via MFMA (all 16 rows identical); returns final h[unit] ----
static __device__ __forceinline__ float canon_phase(
    char* h0t, char* h1t, char* yT,
    const unsigned short* __restrict__ pk,
    const float* __restrict__ wih2, const float* __restrict__ bih2, const float* __restrict__ bhh2,
    bool bwd, int tid)
{
  const int w = tid>>6, lane = tid&63, col = lane&15, krow = lane>>4;
  const int unit = w*16 + col;
  const float cR  = (bih2[unit]     + bhh2[unit])     * LOG2E_F;
  const float cZ  = (bih2[128+unit] + bhh2[128+unit]) * LOG2E_F;
  const float cNI = bih2[256+unit] * (2.0f*LOG2E_F);
  const float cNH = bhh2[256+unit] * (2.0f*LOG2E_F);
  const float wsr = wih2[unit*2]*LOG2E_F,       wcr = wih2[unit*2+1]*LOG2E_F;
  const float wsz = wih2[(128+unit)*2]*LOG2E_F, wcz = wih2[(128+unit)*2+1]*LOG2E_F;
  const float wsn = wih2[(256+unit)*2]*(2.0f*LOG2E_F), wcn = wih2[(256+unit)*2+1]*(2.0f*LOG2E_F);

  s16x8 bw[3][4];
  #pragma unroll
  for (int i=0;i<3;i++)
    #pragma unroll
    for (int kf=0;kf<4;kf++)
      bw[i][kf] = *(const s16x8*)(pk + (size_t)(((i*8+w)*4 + kf)*64 + lane)*8);

  float hreg = 0.f;
  #pragma unroll 1
  for (int st=0; st<L_N; ++st){
    const int o = bwd ? st : (L_N-1-st);          // canonical angle index
    float ang = (float)o * (TWO_PI_F/(float)L_N);
    float sn = __sinf(ang), cs = __cosf(ang);
    const char* hr = (st&1) ? h1t : h0t;
    char*       hw = (st&1) ? h0t : h1t;
    s16x8 a0 = ldsA(hr,lane,0), a1 = ldsA(hr,lane,1), a2 = ldsA(hr,lane,2), a3 = ldsA(hr,lane,3);
    const float aRi = cR + wsr*sn + wcr*cs;
    const float aZi = cZ + wsz*sn + wcz*cs;
    const float aNIi = cNI + wsn*sn + wcn*cs;
    f32x4 aR, aZ, aNH;
    #pragma unroll
    for (int q=0;q<4;q++){ aR[q]=aRi; aZ[q]=aZi; aNH[q]=cNH; }
    aR  = MFMA(a0,bw[0][0],aR);  aR  = MFMA(a1,bw[0][1],aR);  aR  = MFMA(a2,bw[0][2],aR);  aR  = MFMA(a3,bw[0][3],aR);
    aZ  = MFMA(a0,bw[1][0],aZ);  aZ  = MFMA(a1,bw[1][1],aZ);  aZ  = MFMA(a2,bw[1][2],aZ);  aZ  = MFMA(a3,bw[1][3],aZ);
    aNH = MFMA(a0,bw[2][0],aNH); aNH = MFMA(a1,bw[2][1],aNH); aNH = MFMA(a2,bw[2][2],aNH); aNH = MFMA(a3,bw[2][3],aNH);
    float r = sigm2(aR[0]), z = sigm2(aZ[0]);
    float n = ntanh2(fmaf(r, aNH[0], aNIi));
    hreg = fmaf(z, hreg-n, n);
    unsigned short hb16 = (unsigned short)cvtpk(hreg, hreg);
    #pragma unroll
    for (int q=0;q<4;q++)
      *(unsigned short*)(hw + swzByte(krow*4+q, unit)) = hb16;
    int yrow = bwd ? (L_N-1-st) : st;
    if (krow == 0)
      *(unsigned short*)(yT + swzByte(yrow, unit)) = hb16;
    __syncthreads();
  }
  return hreg;
}

// ================= k_gx (+ fused canon block) =================
__global__ __launch_bounds__(512) void k_gx(const float* __restrict__ x,
                                            const unsigned short* __restrict__ pk_wih,
                                            const float* __restrict__ wih,
                                            const int* __restrict__ dstdeg,
                                            const int* __restrict__ accum,
                                            char* __restrict__ gxall,
                                            const unsigned short* __restrict__ pk_whhf,
                                            const unsigned short* __restrict__ pk_whhb,
                                            const float* __restrict__ wih_f, const float* __restrict__ bih_f, const float* __restrict__ bhh_f,
                                            const float* __restrict__ wih_b, const float* __restrict__ bih_b, const float* __restrict__ bhh_b,
                                            const float* __restrict__ bih,   const float* __restrict__ bhh,
                                            float* __restrict__ gposb, float* __restrict__ hc0)
{
  __shared__ char csm[4*4096];   // canon: h0t, h1t, yfT, ybT
  const int tid = threadIdx.x;
  const int w = tid>>6, lane = tid&63, col = lane&15, krow = lane>>4;
  const int unit = w*16 + col;

  if (blockIdx.x == N_NODES/16){
    char* h0t = csm;
    char* h1t = csm + 4096;
    char* yfT = csm + 8192;
    char* ybT = csm + 12288;
    for (int p = tid; p < 2048; p += 512) ((unsigned short*)h0t)[p] = 0;
    __syncthreads();
    float hb_last = canon_phase(h0t, h1t, ybT, pk_whhb, wih_b, bih_b, bhh_b, true, tid);
    for (int p = tid; p < 2048; p += 512) ((unsigned short*)h0t)[p] = 0;
    __syncthreads();
    float hf_last = canon_phase(h0t, h1t, yfT, pk_whhf, wih_f, bih_f, bhh_f, false, tid);

    s16x8 af0 = ldsA(yfT,lane,0), af1 = ldsA(yfT,lane,1), af2 = ldsA(yfT,lane,2), af3 = ldsA(yfT,lane,3);
    s16x8 ab0 = ldsA(ybT,lane,0), ab1 = ldsA(ybT,lane,1), ab2 = ldsA(ybT,lane,2), ab3 = ldsA(ybT,lane,3);
    #pragma unroll
    for (int i=0;i<3;i++){
      const int g = i*128 + unit;
      const float bia = (i<2) ? (bih[g]+bhh[g])*LOG2E_F : bih[g]*(2.0f*LOG2E_F);
      s16x8 byf[4], byb[4];
      #pragma unroll
      for (int kf=0;kf<4;kf++){
        byf[kf] = *(const s16x8*)(pk_wih + (size_t)(((i*8+w)*12 + 4+kf)*64 + lane)*8);
        byb[kf] = *(const s16x8*)(pk_wih + (size_t)(((i*8+w)*12 + 8+kf)*64 + lane)*8);
      }
      f32x4 acc;
      #pragma unroll
      for (int q=0;q<4;q++) acc[q] = bia;
      acc = MFMA(af0,byf[0],acc); acc = MFMA(af1,byf[1],acc);
      acc = MFMA(af2,byf[2],acc); acc = MFMA(af3,byf[3],acc);
      acc = MFMA(ab0,byb[0],acc); acc = MFMA(ab1,byb[1],acc);
      acc = MFMA(ab2,byb[2],acc); acc = MFMA(ab3,byb[3],acc);
      #pragma unroll
      for (int q=0;q<4;q++){
        int row = krow*4+q;
        if (row < L_N)
          gposb[row*G_N + g] = acc[q];
      }
    }
    if (krow == 0)
      hc0[unit] = 0.5f*(hf_last + hb_last);
    return;
  }

  const int m0 = blockIdx.x*16;
  const float dmaxf = (float)accum[0];
  s16x8 a[4];
  #pragma unroll
  for (int kf=0;kf<4;kf++){
    const float* xp = x + (size_t)(m0+col)*H_N + kf*32 + krow*8;
    a[kf] = pack8(*(const float4*)xp, *(const float4*)(xp+4));
  }
  float degn[4];
  #pragma unroll
  for (int q=0;q<4;q++) degn[q] = (float)dstdeg[m0 + krow*4+q] / dmaxf;
  f32x4 accg[3];
  #pragma unroll
  for (int i=0;i<3;i++){
    f32x4 acc; acc[0]=0.f; acc[1]=0.f; acc[2]=0.f; acc[3]=0.f;
    #pragma unroll
    for (int kf=0;kf<4;kf++){
      s16x8 bfr = *(const s16x8*)(pk_wih + (size_t)(((i*8+w)*12 + kf)*64 + lane)*8);
      acc = MFMA(a[kf], bfr, acc);
    }
    accg[i] = acc;
  }
  const float wdR = wih[(size_t)(unit)*DIN_N     + 384] * LOG2E_F;
  const float wdZ = wih[(size_t)(128+unit)*DIN_N + 384] * LOG2E_F;
  const float wdN = wih[(size_t)(256+unit)*DIN_N + 384] * (2.0f*LOG2E_F);
  #pragma unroll
  for (int q=0;q<4;q++){
    const size_t row = (size_t)(m0 + krow*4+q);
    float rv = accg[0][q] + wdR*degn[q];
    float zv = accg[1][q] + wdZ*degn[q];
    float nv = accg[2][q] + wdN*degn[q];
    uint2 rec;
    rec.x = cvtpk(rv, zv);
    rec.y = (unsigned int)(unsigned short)cvtpk(nv, nv);
    *(uint2*)(gxall + row*1024 + unit*8) = rec;
  }
}

// ================= k_fast: main GRU only, canonical walks =================
__global__ __launch_bounds__(512, 4) void k_fast(
    const char* __restrict__ gxall,
    const unsigned short* __restrict__ pk_whh,
    const float* __restrict__ bhh,
    const float* __restrict__ gposb, const float* __restrict__ hc0,
    const int* __restrict__ ssidx,
    const int* __restrict__ wrev, const int* __restrict__ canonFlag,
    float* __restrict__ out, float* __restrict__ ysel)
{
  __shared__ float gposL[L_N*G_N];     // 18432 B; aliased as f32 out-staging post-loop
  __shared__ char  hbf[2*4096];
  __shared__ float hc0L[H_N];
  __shared__ int   nodeL[BSEQ*L_N];    // node*1024 byte offsets
  __shared__ int   canonL[BSEQ];
  __shared__ int   selC[BSEQ];
  __shared__ int   selI[BSEQ*8];
  __shared__ int   selAny;

  const int tid = threadIdx.x;
  const int w = tid>>6, lane = tid&63, col = lane&15, krow = lane>>4;
  const int unit = w*16 + col;
  const int unit8 = unit*8;
  const int seq0 = blockIdx.x*BSEQ;

  if (tid < BSEQ){ selC[tid] = 0; canonL[tid] = canonFlag[seq0+tid]; }
  if (tid == 0) selAny = 0;
  __syncthreads();

  for (int p = tid; p < L_N*G_N; p += 512) gposL[p] = gposb[p];
  if (tid < H_N) hc0L[tid] = hc0[tid];
  for (int p = tid; p < BSEQ*L_N; p += 512)
    nodeL[p] = wrev[(size_t)seq0*L_N + p] << 10;
  if (tid < NSEL){
    int e = ssidx[tid];
    int d = e - seq0;
    if (d >= 0 && d < BSEQ){
      int slot = atomicAdd(&selC[d], 1);
      if (slot < 8) selI[d*8+slot] = tid;
      atomicOr(&selAny, 1);
    }
  }
  __syncthreads();
  {
    float h0 = hc0L[unit];
    unsigned int p0 = cvtpk(h0, h0);
    #pragma unroll
    for (int q=0;q<4;q++)
      *(unsigned short*)(hbf + swzByte(krow*4+q, unit)) = (unsigned short)p0;
  }
  __syncthreads();

  const float cNH = bhh[256+unit] * (2.0f*LOG2E_F);
  const int hasSel = selAny;

  s16x8 bhw[3][4];
  #pragma unroll
  for (int i=0;i<3;i++)
    #pragma unroll
    for (int kf=0;kf<4;kf++)
      bhw[i][kf] = *(const s16x8*)(pk_whh + (size_t)(((i*8+w)*4 + kf)*64 + lane)*8);

  float hreg[4];
  int cf[4], scnt[4], hoff[4];
  #pragma unroll
  for (int q=0;q<4;q++){
    hreg[q] = hc0L[unit];
    cf[q] = canonL[krow*4+q];
    int c = selC[krow*4+q]; if (c > 8) c = 8;
    scnt[q] = c;
    hoff[q] = swzByte(krow*4+q, unit);
  }

  // depth-2 prefetch buffers (single 8B record per gather)
  uint2 gA[4], gB[4];
  #pragma unroll
  for (int q=0;q<4;q++){
    int nb0 = nodeL[(krow*4+q)*L_N + 0];
    int nb1 = nodeL[(krow*4+q)*L_N + 1];
    gA[q] = *(const uint2*)(gxall + nb0 + unit8);
    gB[q] = *(const uint2*)(gxall + nb1 + unit8);
  }

  #pragma unroll
  for (int t=0; t<L_N; ++t){
    const char* hr = hbf + (t&1)*4096;
    char*       hw = hbf + ((t+1)&1)*4096;
    const float gpR = gposL[t*G_N + unit];
    const float gpZ = gposL[t*G_N + 128 + unit];
    const float gpN = gposL[t*G_N + 256 + unit];
    f32x4 aR, aZ, aNI, aNH;
    #pragma unroll
    for (int q=0;q<4;q++){
      const uint2 g = (t&1) ? gB[q] : gA[q];
      aR[q]  = gpR + bfl(g.x);
      aZ[q]  = gpZ + bfh(g.x);
      aNI[q] = gpN + bfl(g.y);
      aNH[q] = cNH;
    }
    if (t+2 < L_N){
      #pragma unroll
      for (int q=0;q<4;q++){
        int nb = nodeL[(krow*4+q)*L_N + t+2];
        if (t&1) gB[q] = *(const uint2*)(gxall + nb + unit8);
        else     gA[q] = *(const uint2*)(gxall + nb + unit8);
      }
    }
    {
      s16x8 a0 = ldsA(hr,lane,0), a1 = ldsA(hr,lane,1), a2 = ldsA(hr,lane,2), a3 = ldsA(hr,lane,3);
      aR  = MFMA(a0,bhw[0][0],aR);  aR  = MFMA(a1,bhw[0][1],aR);  aR  = MFMA(a2,bhw[0][2],aR);  aR  = MFMA(a3,bhw[0][3],aR);
      aZ  = MFMA(a0,bhw[1][0],aZ);  aZ  = MFMA(a1,bhw[1][1],aZ);  aZ  = MFMA(a2,bhw[1][2],aZ);  aZ  = MFMA(a3,bhw[1][3],aZ);
      aNH = MFMA(a0,bhw[2][0],aNH); aNH = MFMA(a1,bhw[2][1],aNH); aNH = MFMA(a2,bhw[2][2],aNH); aNH = MFMA(a3,bhw[2][3],aNH);
    }
    #pragma unroll
    for (int q=0;q<4;q++){
      float r = sigm2(aR[q]), z = sigm2(aZ[q]);
      float n = ntanh2(fmaf(r, aNH[q], aNI[q]));
      hreg[q] = fmaf(z, hreg[q]-n, n);
    }
    if (t < L_N-1){
      unsigned int p01 = cvtpk(hreg[0], hreg[1]);
      unsigned int p23 = cvtpk(hreg[2], hreg[3]);
      *(unsigned short*)(hw + hoff[0]) = (unsigned short)p01;
      *(unsigned short*)(hw + hoff[1]) = (unsigned short)(p01>>16);
      *(unsigned short*)(hw + hoff[2]) = (unsigned short)p23;
      *(unsigned short*)(hw + hoff[3]) = (unsigned short)(p23>>16);
      if (hasSel){
        #pragma unroll
        for (int q=0;q<4;q++){
          const int row = krow*4+q;
          if (cf[q])
            for (int m=0;m<scnt[q];m++)
              ysel[((size_t)selI[row*8+m]*(L_N-1) + t)*H_N + unit] = hreg[q];
        }
      }
      __syncthreads();
    }
  }
  // ---- coalesced out: stage f32 h in LDS (alias gposL), write float4 full lines ----
  __syncthreads();
  {
    float* stg = gposL;
    #pragma unroll
    for (int q=0;q<4;q++)
      stg[(krow*4+q)*H_N + unit] = hreg[q];
  }
  __syncthreads();
  {
    float4 v = ((const float4*)gposL)[tid];
    ((float4*)(out + (size_t)seq0*H_N))[tid] = v;
  }
}

// ================= slow path small-GRU phase (pre-scaled) =================
static __device__ __forceinline__ void small_gru_phase(
    char* smem, const unsigned short* __restrict__ pk,
    const float* __restrict__ wih2, const float* __restrict__ bih2, const float* __restrict__ bhh2,
    bool bwd, char* ySt, float* hreg, int tid)
{
  const int w = tid>>6, lane = tid&63, col = lane&15, krow = lane>>4;
  const int unit = w*16 + col;
  char* hbf = smem + SMEM_HBF;
  const float* uwF = (const float*)(smem + SMEM_UW);

  const float cR  = (bih2[unit]     + bhh2[unit])     * LOG2E_F;
  const float cZ  = (bih2[128+unit] + bhh2[128+unit]) * LOG2E_F;
  const float cNI = bih2[256+unit] * (2.0f*LOG2E_F);
  const float cNH = bhh2[256+unit] * (2.0f*LOG2E_F);
  const float wsr = wih2[unit*2]*LOG2E_F,       wcr = wih2[unit*2+1]*LOG2E_F;
  const float wsz = wih2[(128+unit)*2]*LOG2E_F, wcz = wih2[(128+unit)*2+1]*LOG2E_F;
  const float wsn = wih2[(256+unit)*2]*(2.0f*LOG2E_F), wcn = wih2[(256+unit)*2+1]*(2.0f*LOG2E_F);

  s16x8 bw[3][4];
  #pragma unroll
  for (int i=0;i<3;i++)
    #pragma unroll
    for (int kf=0;kf<4;kf++)
      bw[i][kf] = *(const s16x8*)(pk + (size_t)(((i*8+w)*4 + kf)*64 + lane)*8);

  #pragma unroll 1
  for (int st=0; st<L_N; ++st){
    const int o = bwd ? (L_N-1-st) : st;
    const char* hr = hbf + (st&1)*4096;
    char*       hw = hbf + ((st+1)&1)*4096;
    float sn[4], cs[4];
    #pragma unroll
    for (int q=0;q<4;q++){
      int row = krow*4+q;
      sn[q] = uwF[(o*16+row)*2+0]; cs[q] = uwF[(o*16+row)*2+1];
    }
    s16x8 a0 = ldsA(hr,lane,0), a1 = ldsA(hr,lane,1), a2 = ldsA(hr,lane,2), a3 = ldsA(hr,lane,3);
    f32x4 aR, aZ, aNH;
    #pragma unroll
    for (int q=0;q<4;q++){
      aR[q]  = cR + wsr*sn[q] + wcr*cs[q];
      aZ[q]  = cZ + wsz*sn[q] + wcz*cs[q];
      aNH[q] = cNH;
    }
    aR  = MFMA(a0,bw[0][0],aR);  aR  = MFMA(a1,bw[0][1],aR);  aR  = MFMA(a2,bw[0][2],aR);  aR  = MFMA(a3,bw[0][3],aR);
    aZ  = MFMA(a0,bw[1][0],aZ);  aZ  = MFMA(a1,bw[1][1],aZ);  aZ  = MFMA(a2,bw[1][2],aZ);  aZ  = MFMA(a3,bw[1][3],aZ);
    aNH = MFMA(a0,bw[2][0],aNH); aNH = MFMA(a1,bw[2][1],aNH); aNH = MFMA(a2,bw[2][2],aNH); aNH = MFMA(a3,bw[2][3],aNH);
    #pragma unroll
    for (int q=0;q<4;q++){
      int row = krow*4+q;
      float r = sigm2(aR[q]), z = sigm2(aZ[q]);
      float ni = cNI + wsn*sn[q] + wcn*cs[q];
      float n = ntanh2(fmaf(r, aNH[q], ni));
      float h = fmaf(z, hreg[q]-n, n);
      hreg[q] = h;
      unsigned int pp = cvtpk(h, h);
      *(unsigned short*)(hw + swzByte(row,unit)) = (unsigned short)pp;
      *(unsigned short*)(ySt + st*4096 + swzByte(row,unit)) = (unsigned short)pp;
    }
    __syncthreads();
  }
}

// ================= k_slow: grid-stride over non-canonical walks =================
__global__ __launch_bounds__(512, 2) void k_slow(
    const char* __restrict__ gxall,
    const unsigned short* __restrict__ pk_whhf, const unsigned short* __restrict__ pk_whhb,
    const unsigned short* __restrict__ pk_whh,  const unsigned short* __restrict__ pk_wih,
    const float* __restrict__ wihf, const float* __restrict__ bihf, const float* __restrict__ bhhf,
    const float* __restrict__ wihb, const float* __restrict__ bihb, const float* __restrict__ bhhb,
    const float* __restrict__ bih,  const float* __restrict__ bhh,
    const int* __restrict__ ssidx,
    const int* __restrict__ wrev, const float* __restrict__ uwbuf,
    const int* __restrict__ slowIdx, const int* __restrict__ slowCnt,
    float* __restrict__ out, float* __restrict__ ysel)
{
  extern __shared__ char smem[];
  char*  hbf   = smem + SMEM_HBF;
  float* uwF   = (float*)(smem + SMEM_UW);
  int*   nodeL = (int*)(smem + SMEM_NODE);
  int*   selC  = (int*)(smem + SMEM_SELC);
  int*   selI  = (int*)(smem + SMEM_SELI);
  int*   seqV  = (int*)(smem + SMEM_SEQV);
  int*   validL= (int*)(smem + SMEM_VALID);
  int*   anyP  = (int*)(smem + SMEM_ANY);

  const int cnt = *slowCnt;
  const int tid = threadIdx.x;
  const int w = tid>>6, lane = tid&63, col = lane&15, krow = lane>>4;
  const int unit = w*16 + col;
  const int unit8 = unit*8;

  s16x8 byf[3][4], byb[3][4], bhw[3][4];
  #pragma unroll
  for (int i=0;i<3;i++){
    #pragma unroll
    for (int kf=0;kf<4;kf++){
      byf[i][kf] = *(const s16x8*)(pk_wih + (size_t)(((i*8+w)*12 + 4+kf)*64 + lane)*8);
      byb[i][kf] = *(const s16x8*)(pk_wih + (size_t)(((i*8+w)*12 + 8+kf)*64 + lane)*8);
      bhw[i][kf] = *(const s16x8*)(pk_whh + (size_t)(((i*8+w)*4  +   kf)*64 + lane)*8);
    }
  }
  const float cR  = (bih[unit]     + bhh[unit])     * LOG2E_F;
  const float cZ  = (bih[128+unit] + bhh[128+unit]) * LOG2E_F;
  const float cNI = bih[256+unit] * (2.0f*LOG2E_F);
  const float cNH = bhh[256+unit] * (2.0f*LOG2E_F);

  for (int base = blockIdx.x*SSEQ; base < cnt; base += NSLOWB*SSEQ){

    if (tid < SSEQ){
      int idx = base + tid;
      int v = (idx < cnt) ? 1 : 0;
      seqV[tid]   = v ? slowIdx[idx] : slowIdx[base];
      validL[tid] = v;
      selC[tid] = 0;
    }
    if (tid == 0) *anyP = 0;
    __syncthreads();

    for (int p = tid; p < SSEQ*L_N; p += 512){
      int si = p / L_N, t = p - si*L_N;
      int sq = seqV[si];
      nodeL[p] = wrev[(size_t)sq*L_N + t] << 10;
      uwF[(t*16+si)*2+0] = uwbuf[2*((size_t)sq*L_N + t)+0];
      uwF[(t*16+si)*2+1] = uwbuf[2*((size_t)sq*L_N + t)+1];
    }
    if (tid < NSEL){
      int e = ssidx[tid];
      for (int si=0; si<SSEQ; si++){
        if (validL[si] && seqV[si]==e){
          int slot = atomicAdd(&selC[si], 1);
          if (slot < 8) selI[si*8+slot] = tid;
          atomicOr(anyP, 1);
        }
      }
    }
    #pragma unroll
    for (int q=0;q<4;q++)
      *(unsigned short*)(hbf + swzByte(krow*4+q, unit)) = 0;
    __syncthreads();
    const int hasSel = *anyP;

    float hreg[4] = {0.f,0.f,0.f,0.f};

    small_gru_phase(smem, pk_whhb, wihb, bihb, bhhb, true,  smem+SMEM_YB, hreg, tid);
    float hb[4];
    #pragma unroll
    for (int q=0;q<4;q++){
      hb[q]=hreg[q]; hreg[q]=0.f;
      *(unsigned short*)(hbf + swzByte(krow*4+q, unit)) = 0;
    }
    __syncthreads();
    small_gru_phase(smem, pk_whhf, wihf, bihf, bhhf, false, smem+SMEM_YF, hreg, tid);
    #pragma unroll
    for (int q=0;q<4;q++){
      hreg[q] = 0.5f*(hreg[q]+hb[q]);
      *(unsigned short*)(hbf + swzByte(krow*4+q, unit)) = (unsigned short)cvtpk(hreg[q], hreg[q]);
    }
    __syncthreads();

    uint2 gv[4];
    #pragma unroll
    for (int q=0;q<4;q++){
      int nb = nodeL[(krow*4+q)*L_N + 0];
      gv[q] = *(const uint2*)(gxall + nb + unit8);
    }

    #pragma unroll 1
    for (int t=0; t<L_N; ++t){
      const char* hr = hbf + (t&1)*4096;
      char*       hw = hbf + ((t+1)&1)*4096;
      f32x4 aR, aZ, aNI, aNH;
      #pragma unroll
      for (int q=0;q<4;q++){
        aR[q]  = cR  + bfl(gv[q].x);
        aZ[q]  = cZ  + bfh(gv[q].x);
        aNI[q] = cNI + bfl(gv[q].y);
        aNH[q] = cNH;
      }
      if (t+1 < L_N){
        #pragma unroll
        for (int q=0;q<4;q++){
          int nb = nodeL[(krow*4+q)*L_N + t+1];
          gv[q] = *(const uint2*)(gxall + nb + unit8);
        }
      }
      {
        s16x8 a0 = ldsA(hr,lane,0), a1 = ldsA(hr,lane,1), a2 = ldsA(hr,lane,2), a3 = ldsA(hr,lane,3);
        aR  = MFMA(a0,bhw[0][0],aR);  aR  = MFMA(a1,bhw[0][1],aR);  aR  = MFMA(a2,bhw[0][2],aR);  aR  = MFMA(a3,bhw[0][3],aR);
        aZ  = MFMA(a0,bhw[1][0],aZ);  aZ  = MFMA(a1,bhw[1][1],aZ);  aZ  = MFMA(a2,bhw[1][2],aZ);  aZ  = MFMA(a3,bhw[1][3],aZ);
        aNH = MFMA(a0,bhw[2][0],aNH); aNH = MFMA(a1,bhw[2][1],aNH); aNH = MFMA(a2,bhw[2][2],aNH); aNH = MFMA(a3,bhw[2][3],aNH);
      }
      {
        const char* yfb = smem + SMEM_YF + t*4096;
        s16x8 f0 = ldsA(yfb,lane,0), f1 = ldsA(yfb,lane,1), f2 = ldsA(yfb,lane,2), f3 = ldsA(yfb,lane,3);
        aR  = MFMA(f0,byf[0][0],aR);  aR  = MFMA(f1,byf[0][1],aR);  aR  = MFMA(f2,byf[0][2],aR);  aR  = MFMA(f3,byf[0][3],aR);
        aZ  = MFMA(f0,byf[1][0],aZ);  aZ  = MFMA(f1,byf[1][1],aZ);  aZ  = MFMA(f2,byf[1][2],aZ);  aZ  = MFMA(f3,byf[1][3],aZ);
        aNI = MFMA(f0,byf[2][0],aNI); aNI = MFMA(f1,byf[2][1],aNI); aNI = MFMA(f2,byf[2][2],aNI); aNI = MFMA(f3,byf[2][3],aNI);
      }
      {
        const char* ybb = smem + SMEM_YB + (L_N-1-t)*4096;
        s16x8 g0 = ldsA(ybb,lane,0), g1 = ldsA(ybb,lane,1), g2 = ldsA(ybb,lane,2), g3 = ldsA(ybb,lane,3);
        aR  = MFMA(g0,byb[0][0],aR);  aR  = MFMA(g1,byb[0][1],aR);  aR  = MFMA(g2,byb[0][2],aR);  aR  = MFMA(g3,byb[0][3],aR);
        aZ  = MFMA(g0,byb[1][0],aZ);  aZ  = MFMA(g1,byb[1][1],aZ);  aZ  = MFMA(g2,byb[1][2],aZ);  aZ  = MFMA(g3,byb[1][3],aZ);
        aNI = MFMA(g0,byb[2][0],aNI); aNI = MFMA(g1,byb[2][1],aNI); aNI = MFMA(g2,byb[2][2],aNI); aNI = MFMA(g3,byb[2][3],aNI);
      }
      #pragma unroll
      for (int q=0;q<4;q++){
        const int row = krow*4+q;
        float r = sigm2(aR[q]), z = sigm2(aZ[q]);
        float n = ntanh2(fmaf(r, aNH[q], aNI[q]));
        float h = fmaf(z, hreg[q]-n, n);
        hreg[q] = h;
        *(unsigned short*)(hw + swzByte(row,unit)) = (unsigned short)cvtpk(h, h);
        if (t == L_N-1){
          if (validL[row])
            out[(size_t)seqV[row]*H_N + unit] = h;
        }
      }
      if (hasSel && t < L_N-1){
        #pragma unroll
        for (int q=0;q<4;q++){
          const int row = krow*4+q;
          int c = selC[row]; if (c > 8) c = 8;
          for (int m=0;m<c;m++)
            ysel[((size_t)selI[row*8+m]*(L_N-1) + t)*H_N + unit] = hreg[q];
        }
      }
      __syncthreads();
    }
  }
}

// ================= loss (finalize folded in; chain-broken inner product) =================
__global__ __launch_bounds__(64) void k_loss(
    const float* __restrict__ ysel, const float* __restrict__ y0,
    const int* __restrict__ wrev, const int* __restrict__ ssidx,
    const float* __restrict__ fcw, const float* __restrict__ fcb,
    float* __restrict__ accum, float* __restrict__ out)
{
  const int i = blockIdx.x;
  const int f = threadIdx.x;
  __shared__ __align__(16) float yh[H_N];
  const int seq = ssidx[i];
  float A=0.0f, B=0.0f, Sy=0.0f;
  const float bias = fcb[f];
  const float4* fr = (const float4*)(fcw + (size_t)f*H_N);
  for (int t=0;t<L_N-1;t++){
    for (int k=f;k<H_N;k+=64) yh[k] = ysel[((size_t)i*(L_N-1)+t)*H_N + k];
    __syncthreads();
    float l0=0.f,l1=0.f,l2=0.f,l3=0.f;
    const float4* y4 = (const float4*)yh;
    #pragma unroll 8
    for (int k4=0;k4<H_N/4;k4++){
      float4 wv = fr[k4];
      float4 yv = y4[k4];
      l0 = fmaf(wv.x, yv.x, l0);
      l1 = fmaf(wv.y, yv.y, l1);
      l2 = fmaf(wv.z, yv.z, l2);
      l3 = fmaf(wv.w, yv.w, l3);
    }
    float lg = bias + ((l0+l1)+(l2+l3));
    const int node = wrev[(size_t)seq*L_N + t + 1];
    const float yt = y0[(size_t)node*F_N + f];
    A += yt * softplusf(-lg);
    B += (1.0f-yt) * softplusf(lg);
    Sy += yt;
    __syncthreads();
  }
  for (int off=32; off; off>>=1){
    A += __shfl_down(A,off); B += __shfl_down(B,off); Sy += __shfl_down(Sy,off);
  }
  if (f==0){
    atomicAdd(&accum[1],A); atomicAdd(&accum[2],B); atomicAdd(&accum[3],Sy);
    __threadfence();
    unsigned int done = atomicAdd((unsigned int*)&accum[5], 1u);
    if (done == NSEL-1){
      float As = atomicAdd(&accum[1], 0.0f);
      float Bs = atomicAdd(&accum[2], 0.0f);
      float Ss = atomicAdd(&accum[3], 0.0f);
      out[(size_t)SEQ_N*H_N] = As/Ss + Bs/(float)(NSEL*(L_N-1)*F_N);
    }
  }
}

extern "C" void kernel_launch(void* const* d_in, const int* in_sizes, int n_in,
                              void* d_out, int out_size, void* d_ws, size_t ws_size,
                              hipStream_t stream)
{
  const float* x     = (const float*)d_in[0];
  const float* y0    = (const float*)d_in[1];
  const float* wih_f = (const float*)d_in[2];
  const float* whh_f = (const float*)d_in[3];
  const float* bih_f = (const float*)d_in[4];
  const float* bhh_f = (const float*)d_in[5];
  const float* wih_b = (const float*)d_in[6];
  const float* whh_b = (const float*)d_in[7];
  const float* bih_b = (const float*)d_in[8];
  const float* bhh_b = (const float*)d_in[9];
  const float* wih   = (const float*)d_in[10];
  const float* whh   = (const float*)d_in[11];
  const float* bih   = (const float*)d_in[12];
  const float* bhh   = (const float*)d_in[13];
  const float* fc_w  = (const float*)d_in[14];
  const float* fc_b  = (const float*)d_in[15];
  const int*   walks = (const int*)d_in[16];
  const int*   dstdeg= (const int*)d_in[17];
  const int*   ssidx = (const int*)d_in[18];
  (void)in_sizes; (void)n_in; (void)out_size; (void)ws_size;

  char* ws = (char*)d_ws;
  size_t off = 0;
  auto wsalloc = [&](size_t bytes)->void* {
    void* p = ws + off; off += (bytes + 255) & ~(size_t)255; return p;
  };
  int*   accum_i = (int*)wsalloc(32);   // [0]=degmax [1..3]=loss [4]=slowCnt [5]=done
  float* accum_f = (float*)accum_i;
  int*   wrev   = (int*)  wsalloc(sizeof(int)  * SEQ_N * L_N);
  float* uwbuf  = (float*)wsalloc(sizeof(float)* SEQ_N * L_N * 2);
  unsigned short* pk_whhf = (unsigned short*)wsalloc(2u*24*4*64*8);
  unsigned short* pk_whhb = (unsigned short*)wsalloc(2u*24*4*64*8);
  unsigned short* pk_whh  = (unsigned short*)wsalloc(2u*24*4*64*8);
  unsigned short* pk_wih  = (unsigned short*)wsalloc(2u*24*12*64*8);
  float* ysel   = (float*)wsalloc(sizeof(float)* NSEL * (L_N-1) * H_N);
  char*  gxall  = (char*)wsalloc((size_t)N_NODES*1024);
  int*   canonFlag = (int*)wsalloc(sizeof(int)*SEQ_N);
  int*   slowIdxA  = (int*)wsalloc(sizeof(int)*SEQ_N);
  float* gposb = (float*)wsalloc(sizeof(float)*L_N*G_N);
  float* hc0   = (float*)wsalloc(sizeof(float)*H_N);

  hipMemsetAsync(accum_i, 0, 32, stream);
  k_prep<<<704, 512, 0, stream>>>(
      whh_f, whh_b, whh, wih,
      walks, dstdeg,
      pk_whhf, pk_whhb, pk_whh, pk_wih,
      wrev, uwbuf, accum_i, canonFlag, slowIdxA);
  k_gx<<<N_NODES/16 + 1, 512, 0, stream>>>(x, pk_wih, wih, dstdeg, accum_i, gxall,
      pk_whhf, pk_whhb,
      wih_f, bih_f, bhh_f,
      wih_b, bih_b, bhh_b,
      bih, bhh, gposb, hc0);
  k_fast<<<SEQ_N/BSEQ, 512, 0, stream>>>(gxall, pk_whh, bhh,
      gposb, hc0, ssidx, wrev, canonFlag,
      (float*)d_out, ysel);
  hipFuncSetAttribute(reinterpret_cast<const void*>(k_slow),
                      hipFuncAttributeMaxDynamicSharedMemorySize, SMEM_TOTAL);
  k_slow<<<NSLOWB, 512, SMEM_TOTAL, stream>>>(gxall,
      pk_whhf, pk_whhb, pk_whh, pk_wih,
      wih_f, bih_f, bhh_f,
      wih_b, bih_b, bhh_b,
      bih, bhh,
      ssidx, wrev, uwbuf,
      slowIdxA, accum_i+4,
      (float*)d_out, ysel);
  k_loss<<<NSEL, 64, 0, stream>>>(ysel, y0, wrev, ssidx, fc_w, fc_b, accum_f, (float*)d_out);
}